// Round 22
// baseline (312.499 us; speedup 1.0000x reference)
//
#include <hip/hip_runtime.h>
#include <math.h>

#define NN 50000
#define EE 800000

typedef __attribute__((ext_vector_type(8))) short bf16x8;
typedef __attribute__((ext_vector_type(4))) float f32x4;
typedef __attribute__((ext_vector_type(2))) float f32x2;

__device__ __forceinline__ float bf2f(unsigned int h16) {
  union { unsigned u; float f; } z; z.u = h16 << 16; return z.f;
}
__device__ __forceinline__ float uasf(unsigned u) {
  union { unsigned u; float f; } z; z.u = u; return z.f;
}
__device__ __forceinline__ unsigned cvtpk(float lo, float hi) {
  unsigned r;
  asm("v_cvt_pk_bf16_f32 %0, %1, %2" : "=v"(r) : "v"(lo), "v"(hi));
  return r;
}
__device__ __forceinline__ float frcp(float v) { return __builtin_amdgcn_rcpf(v); }
__device__ __forceinline__ float sigm(float v) { return frcp(1.0f + __expf(-v)); }
__device__ __forceinline__ float ftanh(float x) {
  const float xc = fminf(fmaxf(x, -20.0f), 20.0f);
  const float t = __expf(2.0f * xc);
  return (t - 1.0f) * frcp(t + 1.0f);
}

__device__ __forceinline__ bf16x8 pack8(float a0, float a1, float a2, float a3,
                                        float a4, float a5, float a6, float a7) {
  union { unsigned u[4]; bf16x8 v; } z;
  z.u[0] = cvtpk(a0, a1); z.u[1] = cvtpk(a2, a3);
  z.u[2] = cvtpk(a4, a5); z.u[3] = cvtpk(a6, a7);
  return z.v;
}

// ============ K0: pack all weights into bf16 MFMA A-fragments (standalone) ============
__global__ __launch_bounds__(64) void k0_prep(const float* __restrict__ W1,
                                              const float* __restrict__ W2,
                                              const float* __restrict__ Wih,
                                              const float* __restrict__ Whh,
                                              unsigned short* __restrict__ frags) {
  const int f = blockIdx.x, l = threadIdx.x;
  const int c16 = l & 15, kg = l >> 4;
  float v[8];
  if (f < 8) {
    const int c = f * 16 + c16;
#pragma unroll
    for (int j = 0; j < 8; ++j) {
      const int k = kg * 8 + j;
      v[j] = (k < 20) ? W1[(256 + k) * 128 + c] : 0.0f;
    }
  } else if (f < 40) {
    const int lf = f - 8, ct = lf >> 2, ks = lf & 3, c = ct * 16 + c16;
#pragma unroll
    for (int j = 0; j < 8; ++j) { const int k = ks * 32 + kg * 8 + j; v[j] = W2[k * 128 + c]; }
  } else if (f < 104) {
    const int lf = f - 40, ct = lf >> 2, ks = lf & 3, c = ct * 16 + c16;
#pragma unroll
    for (int j = 0; j < 8; ++j) {
      const int k = ks * 32 + kg * 8 + j;
      v[j] = (c < 128) ? W1[k * 128 + c] : W1[(128 + k) * 128 + (c - 128)];
    }
  } else if (f < 200) {
    const int lf = f - 104, ct = lf >> 2, ks = lf & 3, c = ct * 16 + c16;
#pragma unroll
    for (int j = 0; j < 8; ++j) { const int k = ks * 32 + kg * 8 + j; v[j] = Wih[c * 128 + k]; }
  } else {
    const int lf = f - 200, ct = lf >> 2, ks = lf & 3, c = ct * 16 + c16;
#pragma unroll
    for (int j = 0; j < 8; ++j) { const int k = ks * 32 + kg * 8 + j; v[j] = Whh[c * 128 + k]; }
  }
  *(bf16x8*)(frags + (size_t)f * 512 + l * 8) =
      pack8(v[0], v[1], v[2], v[3], v[4], v[5], v[6], v[7]);
}

// ===== M12: hist (blocks 0..3124) + k1 node-pre + sums-zero (blocks 3125..6249) =====
// hist and k1 are independent; merging overlaps their execution.
__global__ __launch_bounds__(256) void kM12(const int* __restrict__ ei,
                                            int* __restrict__ deg,
                                            const float* __restrict__ x,
                                            const unsigned short* __restrict__ W1nf,
                                            unsigned short* __restrict__ Pd,
                                            unsigned short* __restrict__ Ps,
                                            float* __restrict__ sums) {
  const int bid = blockIdx.x;
  if (bid < 3125) {
    const int e = bid * 256 + threadIdx.x;
    if (e < EE) atomicAdd(&deg[ei[EE + e]], 1);
    return;
  }
  const int b2 = bid - 3125;   // k1 block id, 0..3124
  __shared__ __align__(16) unsigned short sh[16][264];  // [node][Pd(128) | Ps(128)]
  const int t = threadIdx.x, lane = t & 63, w = t >> 6;
  const int kg = lane >> 4, li = lane & 15;
  const int node = b2 * 16 + li;   // 3125*16 = 50000 exact

  // zero this block's slice of sums (16 nodes x 128 cols = 2048 floats)
  {
    const f32x4 z4 = {0.0f, 0.0f, 0.0f, 0.0f};
    float* sz = sums + (size_t)b2 * 2048 + t * 8;
    *(f32x4*)sz = z4;
    *(f32x4*)(sz + 4) = z4;
  }

  const f32x4 zf = {0.0f, 0.0f, 0.0f, 0.0f};
  f32x4 acc[4] = {zf, zf, zf, zf};
#pragma unroll
  for (int ks = 0; ks < 4; ++ks) {
    const float* xp = x + (size_t)node * 128 + ks * 32 + kg * 8;
    const float4 u = *(const float4*)xp, v = *(const float4*)(xp + 4);
    const bf16x8 xb = pack8(u.x, u.y, u.z, u.w, v.x, v.y, v.z, v.w);
#pragma unroll
    for (int i = 0; i < 4; ++i) {
      const int ct = w * 4 + i;
      const bf16x8 af = *(const bf16x8*)(W1nf + (size_t)(ct * 4 + ks) * 512 + lane * 8);
      acc[i] = __builtin_amdgcn_mfma_f32_16x16x32_bf16(af, xb, acc[i], 0, 0, 0);
    }
  }
#pragma unroll
  for (int i = 0; i < 4; ++i) {
    const int C = w * 4 + i;                         // 0..15
    const int off = ((C < 8) ? 0 : 128) + kg * 32 + (C & 7) * 4;
    *(uint2*)&sh[li][off] =
        make_uint2(cvtpk(acc[i][0], acc[i][1]), cvtpk(acc[i][2], acc[i][3]));
  }
  __syncthreads();
  {
    const int nl = t >> 4, cseg = (t & 15) * 8;
    const int gn = b2 * 16 + nl;
    *(uint4*)(Pd + (size_t)gn * 128 + cseg) = *(const uint4*)&sh[nl][cseg];
    *(uint4*)(Ps + (size_t)gn * 128 + cseg) = *(const uint4*)&sh[nl][128 + cseg];
  }
}

// ============ kC3: per-node offsets with direct deg prefix; also zeroes cur ============
__global__ __launch_bounds__(256) void kC_offs3(const int* __restrict__ deg,
                                                int* __restrict__ offs,
                                                int* __restrict__ cur) {
  __shared__ int s[256];
  __shared__ int wred[4];
  const int t = threadIdx.x, b = blockIdx.x, i = b * 256 + t;
  // prefix: total degree of all nodes before this block (deg is L2-resident, 200KB)
  int pre = 0;
  const int lim = b * 256;
  for (int j = t; j < lim; j += 256) pre += deg[j];
#pragma unroll
  for (int o = 32; o > 0; o >>= 1) pre += __shfl_down(pre, o);
  if ((t & 63) == 0) wred[t >> 6] = pre;
  const int orig = (i < NN) ? deg[i] : 0;
  s[t] = orig;
  __syncthreads();
  const int boffb = wred[0] + wred[1] + wred[2] + wred[3];
  for (int o = 1; o < 256; o <<= 1) {
    const int v = (t >= o) ? s[t - o] : 0;
    __syncthreads();
    s[t] += v;
    __syncthreads();
  }
  if (i < NN) { offs[i] = boffb + s[t] - orig; cur[i] = 0; }
}

// prep: one 48B slot per edge in sorted position:
// shorts [0..15]=ea, [16..19]=geom, [20..23]=dst,src (2x u32)
__global__ __launch_bounds__(256) void k_prep_edges(const int* __restrict__ ei,
                                                    const float* __restrict__ edge_attr,
                                                    const float* __restrict__ pos,
                                                    const int* __restrict__ offs,
                                                    int* __restrict__ cur,
                                                    unsigned short* __restrict__ ea_s) {
  const int e = blockIdx.x * 256 + threadIdx.x;
  if (e >= EE) return;
  const int s = ei[e], d = ei[EE + e];
  const int p = offs[d] + atomicAdd(&cur[d], 1);
  const float* ep = edge_attr + (size_t)e * 16;
  const float4 u  = *(const float4*)ep,       v  = *(const float4*)(ep + 4);
  const float4 u2 = *(const float4*)(ep + 8), v2 = *(const float4*)(ep + 12);
  const float rx = (pos[3 * s + 0] - pos[3 * d + 0]) * 0.2f;
  const float ry = (pos[3 * s + 1] - pos[3 * d + 1]) * 0.2f;
  const float rz = (pos[3 * s + 2] - pos[3 * d + 2]) * 0.2f;
  unsigned short* fp = ea_s + (size_t)p * 24;
  *(bf16x8*)(fp)     = pack8(u.x, u.y, u.z, u.w, v.x, v.y, v.z, v.w);
  *(bf16x8*)(fp + 8) = pack8(u2.x, u2.y, u2.z, u2.w, v2.x, v2.y, v2.z, v2.w);
  *(uint4*)(fp + 16) = make_uint4(cvtpk(rx, ry),
                                  cvtpk(rz, rx * rx + ry * ry + rz * rz),
                                  (unsigned)d, (unsigned)s);
}

// ============ K2: fused edge kernel — r19 structure + bijective XCD swizzle ============
__global__ __launch_bounds__(256) void k2_edge(const unsigned short* __restrict__ Pd,
                                               const unsigned short* __restrict__ Ps,
                                               const unsigned short* __restrict__ ea_s,
                                               const unsigned short* __restrict__ W1ef,
                                               const unsigned short* __restrict__ W2f,
                                               const float* __restrict__ b1,
                                               const float* __restrict__ ln1g,
                                               const float* __restrict__ ln1b,
                                               float* __restrict__ sums) {
  __shared__ __align__(16) unsigned short htile[64][136];  // h (bf16), then msg in place
  __shared__ int dsts[64], srcs[64];
  __shared__ int runStart[65];
  __shared__ int runCnt;
  __shared__ __align__(16) float b1s[128];
  __shared__ __align__(16) float g1s[128];
  __shared__ __align__(16) float bb1s[128];

  const int t = threadIdx.x, lane = t & 63, w = t >> 6;
  const int kg = lane >> 4, li = lane & 15;
  // bijective XCD swizzle (nwg = 12500 = 4*1563 + 4*1562): contiguous chunk per XCD
  const int orig = blockIdx.x;
  const int xcd = orig & 7, j = orig >> 3;
  const int bid = (xcd < 4 ? xcd * 1563 : 6252 + (xcd - 4) * 1562) + j;
  const int e0 = bid * 64;          // 12500*64 = 800000 exact
  const int el = w * 16 + li;       // this lane's edge row

  if (t < 128) { b1s[t] = b1[t]; g1s[t] = ln1g[t]; bb1s[t] = ln1b[t]; }
  if (t < 64) {
    const uint2 v = *(const uint2*)(ea_s + (size_t)(e0 + t) * 24 + 20);
    dsts[t] = (int)v.x; srcs[t] = (int)v.y;
  }
  __syncthreads();   // barrier 1

  // ---- run table (wave 0 only): ballot over dst-change flags ----
  if (w == 0) {
    const bool flag = (lane == 0) || (dsts[lane] != dsts[lane - 1]);
    const unsigned long long mask = __ballot(flag);
    const int rid = __popcll(mask & ((1ull << lane) - 1ull));
    if (flag) runStart[rid] = lane;
    if (lane == 63) {
      const int nr = __popcll(mask);
      runCnt = nr;
      runStart[nr] = 64;
    }
  }

  // ---- split-P fragment gathers: 64B/lane contiguous, fully used ----
  const int dn = dsts[el], sn = srcs[el];
  const uint4* pdp = (const uint4*)(Pd + (size_t)dn * 128 + kg * 32);
  const uint4* psp = (const uint4*)(Ps + (size_t)sn * 128 + kg * 32);
  uint4 PV[4] = {pdp[0], pdp[1], pdp[2], pdp[3]};
  uint4 SV[4] = {psp[0], psp[1], psp[2], psp[3]};

  // ---- A1 fragment: from the 48B edge slot; geom fragment built in regs ----
  const unsigned short* slot = ea_s + (size_t)(e0 + el) * 24;
  bf16x8 bfrag;
  if (kg < 2) {
    bfrag = *(const bf16x8*)(slot + kg * 8);
  } else if (kg == 2) {
    const uint2 g = *(const uint2*)(slot + 16);
    union { unsigned u[4]; bf16x8 v; } z;
    z.u[0] = g.x; z.u[1] = g.y; z.u[2] = 0u; z.u[3] = 0u;
    bfrag = z.v;
  } else {
    union { unsigned u[4]; bf16x8 v; } z;
    z.u[0] = 0u; z.u[1] = 0u; z.u[2] = 0u; z.u[3] = 0u;
    bfrag = z.v;
  }

  // ---- A1: acc = (ea|geom) @ W1[256:276] + b1 (b1 as C operand) ----
  f32x4 acc[8];
#pragma unroll
  for (int cf = 0; cf < 8; ++cf) {
    const f32x4 bC = *(const f32x4*)&b1s[cf * 16 + kg * 4];
    const bf16x8 af = *(const bf16x8*)(W1ef + (size_t)cf * 512 + lane * 8);
    acc[cf] = __builtin_amdgcn_mfma_f32_16x16x32_bf16(af, bfrag, bC, 0, 0, 0);
  }

  // ---- A2: acc += Pd + Ps ; LN stats on f32x2 pairs (pk math) ----
  f32x2 sv1 = {0.0f, 0.0f}, sv2 = {0.0f, 0.0f};
#pragma unroll
  for (int q = 0; q < 4; ++q) {
    const unsigned pdx[4] = {PV[q].x, PV[q].y, PV[q].z, PV[q].w};
    const unsigned psx[4] = {SV[q].x, SV[q].y, SV[q].z, SV[q].w};
#pragma unroll
    for (int h2 = 0; h2 < 4; ++h2) {
      const int cf = 2 * q + (h2 >> 1);
      const int j0 = (h2 & 1) * 2;
      f32x2 pd2; pd2[0] = uasf(pdx[h2] << 16); pd2[1] = uasf(pdx[h2] & 0xffff0000u);
      f32x2 ps2; ps2[0] = uasf(psx[h2] << 16); ps2[1] = uasf(psx[h2] & 0xffff0000u);
      f32x2 av;  av[0] = acc[cf][j0]; av[1] = acc[cf][j0 + 1];
      av = av + pd2 + ps2;
      acc[cf][j0] = av[0]; acc[cf][j0 + 1] = av[1];
      sv1 += av;
      sv2 += av * av;
    }
  }
  float s1 = sv1[0] + sv1[1], s2 = sv2[0] + sv2[1];
  s1 += __shfl_xor(s1, 16); s2 += __shfl_xor(s2, 16);
  s1 += __shfl_xor(s1, 32); s2 += __shfl_xor(s2, 32);
  const float m = s1 * (1.0f / 128.0f);
  const float var = s2 * (1.0f / 128.0f) - m * m;
  const float rstd = rsqrtf(var + 1e-5f);
  const f32x2 mneg = {-m, -m};
  const f32x2 rr2 = {rstd, rstd};
#pragma unroll
  for (int cf = 0; cf < 8; ++cf) {
    unsigned ow[2];
#pragma unroll
    for (int p2 = 0; p2 < 2; ++p2) {
      const f32x2 g2 = *(const f32x2*)&g1s[cf * 16 + kg * 4 + p2 * 2];
      const f32x2 be = *(const f32x2*)&bb1s[cf * 16 + kg * 4 + p2 * 2];
      f32x2 xv; xv[0] = acc[cf][p2 * 2]; xv[1] = acc[cf][p2 * 2 + 1];
      f32x2 y = (xv + mneg) * rr2 * g2 + be;
      float y0 = y[0], y1 = y[1];
      y0 *= sigm(y0); y1 *= sigm(y1);
      ow[p2] = cvtpk(y0, y1);
    }
    *(uint2*)&htile[el][cf * 16 + kg * 4] = make_uint2(ow[0], ow[1]);
  }

  // intra-wave LDS ordering (wave's writes land before its cross-lane reads)
  asm volatile("s_waitcnt lgkmcnt(0)" ::: "memory");
  __builtin_amdgcn_sched_barrier(0);

  // ---- B: msg^T = W2^T x h (own rows only), write msg back in place ----
  {
    bf16x8 hfr[4];
#pragma unroll
    for (int ks = 0; ks < 4; ++ks)
      hfr[ks] = *(const bf16x8*)&htile[el][ks * 32 + kg * 8];

    const f32x4 zf = {0.0f, 0.0f, 0.0f, 0.0f};
    f32x4 macc[8];
#pragma unroll
    for (int cf = 0; cf < 8; ++cf) macc[cf] = zf;
#pragma unroll
    for (int ks = 0; ks < 4; ++ks) {
#pragma unroll
      for (int cf = 0; cf < 8; ++cf) {
        const bf16x8 wf = *(const bf16x8*)(W2f + (size_t)((cf << 2) | ks) * 512 + lane * 8);
        macc[cf] = __builtin_amdgcn_mfma_f32_16x16x32_bf16(wf, hfr[ks], macc[cf], 0, 0, 0);
      }
    }
#pragma unroll
    for (int cf = 0; cf < 8; ++cf) {
      *(uint2*)&htile[el][cf * 16 + kg * 4] =
          make_uint2(cvtpk(macc[cf][0], macc[cf][1]), cvtpk(macc[cf][2], macc[cf][3]));
    }
  }
  __syncthreads();   // barrier 2

  // ---- C: run-table segmented reduce on column pairs (b32 + pk adds) ----
  {
    const int nruns = runCnt;
    const int ntask = nruns << 6;            // nruns * 64 col-pairs
    for (int base = w * 64; base < ntask; base += 256) {
      const int run = base >> 6;             // wave-uniform
      const int cp = lane;                   // col pair 0..63
      const int s    = __builtin_amdgcn_readfirstlane(runStart[run]);
      const int epos = __builtin_amdgcn_readfirstlane(runStart[run + 1]);
      const int dd   = __builtin_amdgcn_readfirstlane(dsts[s]);
      f32x2 racc = {0.0f, 0.0f};
      for (int e = s; e < epos; ++e) {
        const unsigned vv = *(const unsigned*)&htile[e][cp * 2];
        f32x2 f; f[0] = uasf(vv << 16); f[1] = uasf(vv & 0xffff0000u);
        racc += f;
      }
      atomicAdd(sums + (size_t)dd * 128 + cp * 2,     racc[0]);
      atomicAdd(sums + (size_t)dd * 128 + cp * 2 + 1, racc[1]);
    }
  }
}

// ============ K3: GRU + LN2 (MFMA), 32 nodes per block, 8 waves ============
__global__ __launch_bounds__(512) void k3_gru(const float* __restrict__ x,
                                              const float* __restrict__ sums,
                                              const int* __restrict__ deg,
                                              const unsigned short* __restrict__ Wihf,
                                              const unsigned short* __restrict__ Whhf,
                                              const float* __restrict__ bih,
                                              const float* __restrict__ bhh,
                                              const float* __restrict__ b2,
                                              const float* __restrict__ ln2g,
                                              const float* __restrict__ ln2b,
                                              float* __restrict__ out) {
  __shared__ unsigned short aggb[32][136];
  __shared__ unsigned short Ss[32][776];
  const int t = threadIdx.x, lane = t & 63, w = t >> 6;
  const int kg = lane >> 4, li = lane & 15;
  const int n0 = blockIdx.x * 32;

  {
    const int nl = t >> 4, c0 = (t & 15) * 8;
    const int gn = n0 + nl;
    uint4 o = make_uint4(0, 0, 0, 0);
    if (gn < NN) {
      const int dc = deg[gn];
      const float inv = frcp(fmaxf((float)dc, 1.0f));
      const float bsc = (dc > 0) ? 1.0f : 0.0f;
      const float* sp = sums + (size_t)gn * 128 + c0;
      const float4 u = *(const float4*)sp, v = *(const float4*)(sp + 4);
      const float4 bu = *(const float4*)(b2 + c0), bv = *(const float4*)(b2 + c0 + 4);
      o.x = cvtpk(u.x * inv + bsc * bu.x, u.y * inv + bsc * bu.y);
      o.y = cvtpk(u.z * inv + bsc * bu.z, u.w * inv + bsc * bu.w);
      o.z = cvtpk(v.x * inv + bsc * bv.x, v.y * inv + bsc * bv.y);
      o.w = cvtpk(v.z * inv + bsc * bv.z, v.w * inv + bsc * bv.w);
    }
    *(uint4*)&aggb[nl][c0] = o;
  }
  __syncthreads();

  const int nh = w >> 2;
  const int isH = (w >> 1) & 1;
  const int ctbase = (w & 1) * 12;
  const int nodeL = nh * 16 + li;
  const int gnode = n0 + nodeL;
  const unsigned short* Wf = isH ? Whhf : Wihf;
  const float* bias = isH ? bhh : bih;
  const f32x4 zf = {0.0f, 0.0f, 0.0f, 0.0f};
  f32x4 acc[12];
#pragma unroll
  for (int i = 0; i < 12; ++i) acc[i] = zf;
#pragma unroll
  for (int ks = 0; ks < 4; ++ks) {
    bf16x8 bfrag;
    if (isH) {
      if (gnode < NN) {
        const float* xp = x + (size_t)gnode * 128 + ks * 32 + kg * 8;
        const float4 u = *(const float4*)xp, v = *(const float4*)(xp + 4);
        bfrag = pack8(u.x, u.y, u.z, u.w, v.x, v.y, v.z, v.w);
      } else {
        bfrag = pack8(0.f, 0.f, 0.f, 0.f, 0.f, 0.f, 0.f, 0.f);
      }
    } else {
      bfrag = *(const bf16x8*)&aggb[nodeL][ks * 32 + kg * 8];
    }
#pragma unroll
    for (int i = 0; i < 12; ++i) {
      const int ct = ctbase + i;
      const bf16x8 af = *(const bf16x8*)(Wf + (size_t)(ct * 4 + ks) * 512 + lane * 8);
      acc[i] = __builtin_amdgcn_mfma_f32_16x16x32_bf16(af, bfrag, acc[i], 0, 0, 0);
    }
  }
#pragma unroll
  for (int i = 0; i < 12; ++i) {
    const int ocol = (ctbase + i) * 16 + kg * 4;
    const float4 bb = *(const float4*)(bias + ocol);
    const int col = isH * 384 + ocol;
    const unsigned lo = cvtpk(acc[i][0] + bb.x, acc[i][1] + bb.y);
    const unsigned hi = cvtpk(acc[i][2] + bb.z, acc[i][3] + bb.w);
    *(uint2*)&Ss[nodeL][col] = make_uint2(lo, hi);
  }
  __syncthreads();

  const int nl = t >> 4, q0 = (t & 15) * 8;
  const int gn = n0 + nl;
  if (gn < NN) {
    float xv[8];
    *(float4*)&xv[0] = *(const float4*)(x + (size_t)gn * 128 + q0);
    *(float4*)&xv[4] = *(const float4*)(x + (size_t)gn * 128 + q0 + 4);
    const uint4 gir = *(const uint4*)&Ss[nl][q0];
    const uint4 giz = *(const uint4*)&Ss[nl][q0 + 128];
    const uint4 gin = *(const uint4*)&Ss[nl][q0 + 256];
    const uint4 ghr = *(const uint4*)&Ss[nl][q0 + 384];
    const uint4 ghz = *(const uint4*)&Ss[nl][q0 + 512];
    const uint4 ghn = *(const uint4*)&Ss[nl][q0 + 640];
    const unsigned GIR[4] = {gir.x, gir.y, gir.z, gir.w};
    const unsigned GIZ[4] = {giz.x, giz.y, giz.z, giz.w};
    const unsigned GIN[4] = {gin.x, gin.y, gin.z, gin.w};
    const unsigned GHR[4] = {ghr.x, ghr.y, ghr.z, ghr.w};
    const unsigned GHZ[4] = {ghz.x, ghz.y, ghz.z, ghz.w};
    const unsigned GHN[4] = {ghn.x, ghn.y, ghn.z, ghn.w};
    float vb[8];
    float s1 = 0.0f, s2 = 0.0f;
#pragma unroll
    for (int j2 = 0; j2 < 4; ++j2) {
#pragma unroll
      for (int hl = 0; hl < 2; ++hl) {
        const int jj = j2 * 2 + hl;
        const unsigned sh = hl * 16;
        const float girv = bf2f((GIR[j2] >> sh) & 0xffffu);
        const float gizv = bf2f((GIZ[j2] >> sh) & 0xffffu);
        const float ginv = bf2f((GIN[j2] >> sh) & 0xffffu);
        const float ghrv = bf2f((GHR[j2] >> sh) & 0xffffu);
        const float ghzv = bf2f((GHZ[j2] >> sh) & 0xffffu);
        const float ghnv = bf2f((GHN[j2] >> sh) & 0xffffu);
        const float r = sigm(girv + ghrv);
        const float z = sigm(gizv + ghzv);
        const float nv = ftanh(ginv + r * ghnv);
        const float v = xv[jj] + (1.0f - z) * nv + z * xv[jj];
        vb[jj] = v; s1 += v; s2 += v * v;
      }
    }
    s1 += __shfl_xor(s1, 1); s2 += __shfl_xor(s2, 1);
    s1 += __shfl_xor(s1, 2); s2 += __shfl_xor(s2, 2);
    s1 += __shfl_xor(s1, 4); s2 += __shfl_xor(s2, 4);
    s1 += __shfl_xor(s1, 8); s2 += __shfl_xor(s2, 8);
    const float m = s1 * (1.0f / 128.0f);
    const float var = s2 * (1.0f / 128.0f) - m * m;
    const float rstd = rsqrtf(var + 1e-5f);
    float ov[8];
#pragma unroll
    for (int j = 0; j < 8; ++j)
      ov[j] = ln2g[q0 + j] * ((vb[j] - m) * rstd) + ln2b[q0 + j];
    *(float4*)(out + (size_t)gn * 128 + q0) = make_float4(ov[0], ov[1], ov[2], ov[3]);
    *(float4*)(out + (size_t)gn * 128 + q0 + 4) = make_float4(ov[4], ov[5], ov[6], ov[7]);
  }
}

extern "C" void kernel_launch(void* const* d_in, const int* in_sizes, int n_in,
                              void* d_out, int out_size, void* d_ws, size_t ws_size,
                              hipStream_t stream) {
  const float* x         = (const float*)d_in[0];
  const float* edge_attr = (const float*)d_in[1];
  const float* pos       = (const float*)d_in[2];
  const float* W1        = (const float*)d_in[3];
  const float* b1        = (const float*)d_in[4];
  const float* ln1g      = (const float*)d_in[5];
  const float* ln1b      = (const float*)d_in[6];
  const float* W2        = (const float*)d_in[7];
  const float* b2        = (const float*)d_in[8];
  const float* Wih       = (const float*)d_in[9];
  const float* bih       = (const float*)d_in[10];
  const float* Whh       = (const float*)d_in[11];
  const float* bhh       = (const float*)d_in[12];
  const float* ln2g      = (const float*)d_in[13];
  const float* ln2b      = (const float*)d_in[14];
  const int*   ei        = (const int*)d_in[15];
  float* out = (float*)d_out;

  // ws layout (bytes); ws_size >= 109.9 MB proven (r10 f32p branch executed).
  float*          sums  = (float*)d_ws;                                   // 25,600,000
  int*            deg   = (int*)((char*)d_ws + 25600000);                 //    200,000
  int*            cur   = (int*)((char*)d_ws + 25800000);                 //    200,000
  unsigned short* Pdb   = (unsigned short*)((char*)d_ws + 26000000);      // 12,800,000
  unsigned short* Psb   = (unsigned short*)((char*)d_ws + 38800000);      // 12,800,000
  unsigned short* frags = (unsigned short*)((char*)d_ws + 51600000);      //    303,104
  int*            offs  = (int*)((char*)d_ws + 52000000);                 //    200,000
  unsigned short* ea_s  = (unsigned short*)((char*)d_ws + 52300032);      // 38,400,000 -> 90.7MB
  unsigned short* W1ef = frags;               // 8 frags
  unsigned short* W2f  = frags + 8 * 512;     // 32 frags
  unsigned short* W1nf = frags + 40 * 512;    // 64 frags
  unsigned short* Wihf = frags + 104 * 512;   // 96 frags
  unsigned short* Whhf = frags + 200 * 512;   // 96 frags

  hipMemsetAsync(deg, 0, 200000, stream);       // deg only (cur zeroed in kC_offs3)

  k0_prep<<<296, 64, 0, stream>>>(W1, W2, Wih, Whh, frags);
  kM12<<<6250, 256, 0, stream>>>(ei, deg, x, W1nf, Pdb, Psb, sums);
  kC_offs3<<<196, 256, 0, stream>>>(deg, offs, cur);
  k_prep_edges<<<3125, 256, 0, stream>>>(ei, edge_attr, pos, offs, cur, ea_s);
  k2_edge<<<12500, 256, 0, stream>>>(Pdb, Psb, ea_s,
                                     W1ef, W2f, b1, ln1g, ln1b, sums);
  k3_gru<<<1563, 512, 0, stream>>>(x, sums, deg, Wihf, Whhf, bih, bhh, b2,
                                   ln2g, ln2b, out);
}

// Round 23
// 288.488 us; speedup vs baseline: 1.0832x; 1.0832x over previous
//
#include <hip/hip_runtime.h>
#include <math.h>

#define NN 50000
#define EE 800000

typedef __attribute__((ext_vector_type(8))) short bf16x8;
typedef __attribute__((ext_vector_type(4))) float f32x4;
typedef __attribute__((ext_vector_type(2))) float f32x2;

__device__ __forceinline__ float bf2f(unsigned int h16) {
  union { unsigned u; float f; } z; z.u = h16 << 16; return z.f;
}
__device__ __forceinline__ float uasf(unsigned u) {
  union { unsigned u; float f; } z; z.u = u; return z.f;
}
__device__ __forceinline__ unsigned cvtpk(float lo, float hi) {
  unsigned r;
  asm("v_cvt_pk_bf16_f32 %0, %1, %2" : "=v"(r) : "v"(lo), "v"(hi));
  return r;
}
__device__ __forceinline__ float frcp(float v) { return __builtin_amdgcn_rcpf(v); }
__device__ __forceinline__ float sigm(float v) { return frcp(1.0f + __expf(-v)); }
__device__ __forceinline__ float ftanh(float x) {
  const float xc = fminf(fmaxf(x, -20.0f), 20.0f);
  const float t = __expf(2.0f * xc);
  return (t - 1.0f) * frcp(t + 1.0f);
}

__device__ __forceinline__ bf16x8 pack8(float a0, float a1, float a2, float a3,
                                        float a4, float a5, float a6, float a7) {
  union { unsigned u[4]; bf16x8 v; } z;
  z.u[0] = cvtpk(a0, a1); z.u[1] = cvtpk(a2, a3);
  z.u[2] = cvtpk(a4, a5); z.u[3] = cvtpk(a6, a7);
  return z.v;
}

// ============ M1: hist (blocks 0..3124) + weight-frag pack (blocks 3125..3420) ============
__global__ __launch_bounds__(256) void kM_hist_prep(const int* __restrict__ ei,
                                                    int* __restrict__ deg,
                                                    const float* __restrict__ W1,
                                                    const float* __restrict__ W2,
                                                    const float* __restrict__ Wih,
                                                    const float* __restrict__ Whh,
                                                    unsigned short* __restrict__ frags) {
  const int bid = blockIdx.x;
  if (bid < 3125) {
    const int e = bid * 256 + threadIdx.x;
    if (e < EE) atomicAdd(&deg[ei[EE + e]], 1);
    return;
  }
  const int f = bid - 3125, l = threadIdx.x;
  if (l >= 64) return;
  const int c16 = l & 15, kg = l >> 4;
  float v[8];
  if (f < 8) {
    const int c = f * 16 + c16;
#pragma unroll
    for (int j = 0; j < 8; ++j) {
      const int k = kg * 8 + j;
      v[j] = (k < 20) ? W1[(256 + k) * 128 + c] : 0.0f;
    }
  } else if (f < 40) {
    const int lf = f - 8, ct = lf >> 2, ks = lf & 3, c = ct * 16 + c16;
#pragma unroll
    for (int j = 0; j < 8; ++j) { const int k = ks * 32 + kg * 8 + j; v[j] = W2[k * 128 + c]; }
  } else if (f < 104) {
    const int lf = f - 40, ct = lf >> 2, ks = lf & 3, c = ct * 16 + c16;
#pragma unroll
    for (int j = 0; j < 8; ++j) {
      const int k = ks * 32 + kg * 8 + j;
      v[j] = (c < 128) ? W1[k * 128 + c] : W1[(128 + k) * 128 + (c - 128)];
    }
  } else if (f < 200) {
    const int lf = f - 104, ct = lf >> 2, ks = lf & 3, c = ct * 16 + c16;
#pragma unroll
    for (int j = 0; j < 8; ++j) { const int k = ks * 32 + kg * 8 + j; v[j] = Wih[c * 128 + k]; }
  } else {
    const int lf = f - 200, ct = lf >> 2, ks = lf & 3, c = ct * 16 + c16;
#pragma unroll
    for (int j = 0; j < 8; ++j) { const int k = ks * 32 + kg * 8 + j; v[j] = Whh[c * 128 + k]; }
  }
  *(bf16x8*)(frags + (size_t)f * 512 + l * 8) =
      pack8(v[0], v[1], v[2], v[3], v[4], v[5], v[6], v[7]);
}

// ===== M2: k1 node-pre + sums-zero (blocks 0..3124) + kA block-sum (3125..3320) =====
__global__ __launch_bounds__(256) void kM_k1_partial(const float* __restrict__ x,
                                                     const unsigned short* __restrict__ W1nf,
                                                     unsigned short* __restrict__ Pd,
                                                     unsigned short* __restrict__ Ps,
                                                     const int* __restrict__ deg,
                                                     int* __restrict__ bsum,
                                                     float* __restrict__ sums) {
  const int bid = blockIdx.x;
  if (bid >= 3125) {
    const int i = (bid - 3125) * 256 + threadIdx.x;
    int v = (i < NN) ? deg[i] : 0;
#pragma unroll
    for (int o = 32; o > 0; o >>= 1) v += __shfl_down(v, o);
    __shared__ int wsum[4];
    if ((threadIdx.x & 63) == 0) wsum[threadIdx.x >> 6] = v;
    __syncthreads();
    if (threadIdx.x == 0) bsum[bid - 3125] = wsum[0] + wsum[1] + wsum[2] + wsum[3];
    return;
  }
  __shared__ __align__(16) unsigned short sh[16][264];  // [node][Pd(128) | Ps(128)]
  const int t = threadIdx.x, lane = t & 63, w = t >> 6;
  const int kg = lane >> 4, li = lane & 15;
  const int node = bid * 16 + li;   // 3125*16 = 50000 exact

  // zero this block's slice of sums (16 nodes x 128 cols = 2048 floats)
  {
    const f32x4 z4 = {0.0f, 0.0f, 0.0f, 0.0f};
    float* sz = sums + (size_t)bid * 2048 + t * 8;
    *(f32x4*)sz = z4;
    *(f32x4*)(sz + 4) = z4;
  }

  const f32x4 zf = {0.0f, 0.0f, 0.0f, 0.0f};
  f32x4 acc[4] = {zf, zf, zf, zf};
#pragma unroll
  for (int ks = 0; ks < 4; ++ks) {
    const float* xp = x + (size_t)node * 128 + ks * 32 + kg * 8;
    const float4 u = *(const float4*)xp, v = *(const float4*)(xp + 4);
    const bf16x8 xb = pack8(u.x, u.y, u.z, u.w, v.x, v.y, v.z, v.w);
#pragma unroll
    for (int i = 0; i < 4; ++i) {
      const int ct = w * 4 + i;
      const bf16x8 af = *(const bf16x8*)(W1nf + (size_t)(ct * 4 + ks) * 512 + lane * 8);
      acc[i] = __builtin_amdgcn_mfma_f32_16x16x32_bf16(af, xb, acc[i], 0, 0, 0);
    }
  }
#pragma unroll
  for (int i = 0; i < 4; ++i) {
    const int C = w * 4 + i;                         // 0..15
    const int off = ((C < 8) ? 0 : 128) + kg * 32 + (C & 7) * 4;
    *(uint2*)&sh[li][off] =
        make_uint2(cvtpk(acc[i][0], acc[i][1]), cvtpk(acc[i][2], acc[i][3]));
  }
  __syncthreads();
  {
    const int nl = t >> 4, cseg = (t & 15) * 8;
    const int gn = bid * 16 + nl;
    *(uint4*)(Pd + (size_t)gn * 128 + cseg) = *(const uint4*)&sh[nl][cseg];
    *(uint4*)(Ps + (size_t)gn * 128 + cseg) = *(const uint4*)&sh[nl][128 + cseg];
  }
}

// ============ kC2: fused prefix (bsum partial-sum in-block) + per-node offsets ============
__global__ __launch_bounds__(256) void kC_offs2(const int* __restrict__ deg,
                                                const int* __restrict__ bsum,
                                                int* __restrict__ offs) {
  __shared__ int s[256];
  __shared__ int wred[4];
  const int t = threadIdx.x, b = blockIdx.x, i = b * 256 + t;
  int pre = 0;
  for (int j = t; j < b; j += 256) pre += bsum[j];
#pragma unroll
  for (int o = 32; o > 0; o >>= 1) pre += __shfl_down(pre, o);
  if ((t & 63) == 0) wred[t >> 6] = pre;
  const int orig = (i < NN) ? deg[i] : 0;
  s[t] = orig;
  __syncthreads();
  const int boffb = wred[0] + wred[1] + wred[2] + wred[3];
  for (int o = 1; o < 256; o <<= 1) {
    const int v = (t >= o) ? s[t - o] : 0;
    __syncthreads();
    s[t] += v;
    __syncthreads();
  }
  if (i < NN) offs[i] = boffb + s[t] - orig;
}

// prep: one 48B slot per edge in sorted position:
// shorts [0..15]=ea, [16..19]=geom, [20..23]=dst,src (2x u32)
__global__ __launch_bounds__(256) void k_prep_edges(const int* __restrict__ ei,
                                                    const float* __restrict__ edge_attr,
                                                    const float* __restrict__ pos,
                                                    const int* __restrict__ offs,
                                                    int* __restrict__ cur,
                                                    unsigned short* __restrict__ ea_s) {
  const int e = blockIdx.x * 256 + threadIdx.x;
  if (e >= EE) return;
  const int s = ei[e], d = ei[EE + e];
  const int p = offs[d] + atomicAdd(&cur[d], 1);
  const float* ep = edge_attr + (size_t)e * 16;
  const float4 u  = *(const float4*)ep,       v  = *(const float4*)(ep + 4);
  const float4 u2 = *(const float4*)(ep + 8), v2 = *(const float4*)(ep + 12);
  const float rx = (pos[3 * s + 0] - pos[3 * d + 0]) * 0.2f;
  const float ry = (pos[3 * s + 1] - pos[3 * d + 1]) * 0.2f;
  const float rz = (pos[3 * s + 2] - pos[3 * d + 2]) * 0.2f;
  unsigned short* fp = ea_s + (size_t)p * 24;
  *(bf16x8*)(fp)     = pack8(u.x, u.y, u.z, u.w, v.x, v.y, v.z, v.w);
  *(bf16x8*)(fp + 8) = pack8(u2.x, u2.y, u2.z, u2.w, v2.x, v2.y, v2.z, v2.w);
  *(uint4*)(fp + 16) = make_uint4(cvtpk(rx, ry),
                                  cvtpk(rz, rx * rx + ry * ry + rz * rz),
                                  (unsigned)d, (unsigned)s);
}

// ============ K2: fused edge kernel — r19 structure + bijective XCD swizzle ============
__global__ __launch_bounds__(256) void k2_edge(const unsigned short* __restrict__ Pd,
                                               const unsigned short* __restrict__ Ps,
                                               const unsigned short* __restrict__ ea_s,
                                               const unsigned short* __restrict__ W1ef,
                                               const unsigned short* __restrict__ W2f,
                                               const float* __restrict__ b1,
                                               const float* __restrict__ ln1g,
                                               const float* __restrict__ ln1b,
                                               float* __restrict__ sums) {
  __shared__ __align__(16) unsigned short htile[64][136];  // h (bf16), then msg in place
  __shared__ int dsts[64], srcs[64];
  __shared__ int runStart[65];
  __shared__ int runCnt;
  __shared__ __align__(16) float b1s[128];
  __shared__ __align__(16) float g1s[128];
  __shared__ __align__(16) float bb1s[128];

  const int t = threadIdx.x, lane = t & 63, w = t >> 6;
  const int kg = lane >> 4, li = lane & 15;
  // bijective XCD swizzle (nwg = 12500 = 4*1563 + 4*1562): contiguous chunk per XCD
  const int orig = blockIdx.x;
  const int xcd = orig & 7, j = orig >> 3;
  const int bid = (xcd < 4 ? xcd * 1563 : 6252 + (xcd - 4) * 1562) + j;
  const int e0 = bid * 64;          // 12500*64 = 800000 exact
  const int el = w * 16 + li;       // this lane's edge row

  if (t < 128) { b1s[t] = b1[t]; g1s[t] = ln1g[t]; bb1s[t] = ln1b[t]; }
  if (t < 64) {
    const uint2 v = *(const uint2*)(ea_s + (size_t)(e0 + t) * 24 + 20);
    dsts[t] = (int)v.x; srcs[t] = (int)v.y;
  }
  __syncthreads();   // barrier 1

  // ---- run table (wave 0 only): ballot over dst-change flags ----
  if (w == 0) {
    const bool flag = (lane == 0) || (dsts[lane] != dsts[lane - 1]);
    const unsigned long long mask = __ballot(flag);
    const int rid = __popcll(mask & ((1ull << lane) - 1ull));
    if (flag) runStart[rid] = lane;
    if (lane == 63) {
      const int nr = __popcll(mask);
      runCnt = nr;
      runStart[nr] = 64;
    }
  }

  // ---- split-P fragment gathers: 64B/lane contiguous, fully used ----
  const int dn = dsts[el], sn = srcs[el];
  const uint4* pdp = (const uint4*)(Pd + (size_t)dn * 128 + kg * 32);
  const uint4* psp = (const uint4*)(Ps + (size_t)sn * 128 + kg * 32);
  uint4 PV[4] = {pdp[0], pdp[1], pdp[2], pdp[3]};
  uint4 SV[4] = {psp[0], psp[1], psp[2], psp[3]};

  // ---- A1 fragment: from the 48B edge slot; geom fragment built in regs ----
  const unsigned short* slot = ea_s + (size_t)(e0 + el) * 24;
  bf16x8 bfrag;
  if (kg < 2) {
    bfrag = *(const bf16x8*)(slot + kg * 8);
  } else if (kg == 2) {
    const uint2 g = *(const uint2*)(slot + 16);
    union { unsigned u[4]; bf16x8 v; } z;
    z.u[0] = g.x; z.u[1] = g.y; z.u[2] = 0u; z.u[3] = 0u;
    bfrag = z.v;
  } else {
    union { unsigned u[4]; bf16x8 v; } z;
    z.u[0] = 0u; z.u[1] = 0u; z.u[2] = 0u; z.u[3] = 0u;
    bfrag = z.v;
  }

  // ---- A1: acc = (ea|geom) @ W1[256:276] + b1 (b1 as C operand) ----
  f32x4 acc[8];
#pragma unroll
  for (int cf = 0; cf < 8; ++cf) {
    const f32x4 bC = *(const f32x4*)&b1s[cf * 16 + kg * 4];
    const bf16x8 af = *(const bf16x8*)(W1ef + (size_t)cf * 512 + lane * 8);
    acc[cf] = __builtin_amdgcn_mfma_f32_16x16x32_bf16(af, bfrag, bC, 0, 0, 0);
  }

  // ---- A2: acc += Pd + Ps ; LN stats on f32x2 pairs (pk math) ----
  f32x2 sv1 = {0.0f, 0.0f}, sv2 = {0.0f, 0.0f};
#pragma unroll
  for (int q = 0; q < 4; ++q) {
    const unsigned pdx[4] = {PV[q].x, PV[q].y, PV[q].z, PV[q].w};
    const unsigned psx[4] = {SV[q].x, SV[q].y, SV[q].z, SV[q].w};
#pragma unroll
    for (int h2 = 0; h2 < 4; ++h2) {
      const int cf = 2 * q + (h2 >> 1);
      const int j0 = (h2 & 1) * 2;
      f32x2 pd2; pd2[0] = uasf(pdx[h2] << 16); pd2[1] = uasf(pdx[h2] & 0xffff0000u);
      f32x2 ps2; ps2[0] = uasf(psx[h2] << 16); ps2[1] = uasf(psx[h2] & 0xffff0000u);
      f32x2 av;  av[0] = acc[cf][j0]; av[1] = acc[cf][j0 + 1];
      av = av + pd2 + ps2;
      acc[cf][j0] = av[0]; acc[cf][j0 + 1] = av[1];
      sv1 += av;
      sv2 += av * av;
    }
  }
  float s1 = sv1[0] + sv1[1], s2 = sv2[0] + sv2[1];
  s1 += __shfl_xor(s1, 16); s2 += __shfl_xor(s2, 16);
  s1 += __shfl_xor(s1, 32); s2 += __shfl_xor(s2, 32);
  const float m = s1 * (1.0f / 128.0f);
  const float var = s2 * (1.0f / 128.0f) - m * m;
  const float rstd = rsqrtf(var + 1e-5f);
  const f32x2 mneg = {-m, -m};
  const f32x2 rr2 = {rstd, rstd};
#pragma unroll
  for (int cf = 0; cf < 8; ++cf) {
    unsigned ow[2];
#pragma unroll
    for (int p2 = 0; p2 < 2; ++p2) {
      const f32x2 g2 = *(const f32x2*)&g1s[cf * 16 + kg * 4 + p2 * 2];
      const f32x2 be = *(const f32x2*)&bb1s[cf * 16 + kg * 4 + p2 * 2];
      f32x2 xv; xv[0] = acc[cf][p2 * 2]; xv[1] = acc[cf][p2 * 2 + 1];
      f32x2 y = (xv + mneg) * rr2 * g2 + be;
      float y0 = y[0], y1 = y[1];
      y0 *= sigm(y0); y1 *= sigm(y1);
      ow[p2] = cvtpk(y0, y1);
    }
    *(uint2*)&htile[el][cf * 16 + kg * 4] = make_uint2(ow[0], ow[1]);
  }

  // intra-wave LDS ordering (wave's writes land before its cross-lane reads)
  asm volatile("s_waitcnt lgkmcnt(0)" ::: "memory");
  __builtin_amdgcn_sched_barrier(0);

  // ---- B: msg^T = W2^T x h (own rows only), write msg back in place ----
  {
    bf16x8 hfr[4];
#pragma unroll
    for (int ks = 0; ks < 4; ++ks)
      hfr[ks] = *(const bf16x8*)&htile[el][ks * 32 + kg * 8];

    const f32x4 zf = {0.0f, 0.0f, 0.0f, 0.0f};
    f32x4 macc[8];
#pragma unroll
    for (int cf = 0; cf < 8; ++cf) macc[cf] = zf;
#pragma unroll
    for (int ks = 0; ks < 4; ++ks) {
#pragma unroll
      for (int cf = 0; cf < 8; ++cf) {
        const bf16x8 wf = *(const bf16x8*)(W2f + (size_t)((cf << 2) | ks) * 512 + lane * 8);
        macc[cf] = __builtin_amdgcn_mfma_f32_16x16x32_bf16(wf, hfr[ks], macc[cf], 0, 0, 0);
      }
    }
#pragma unroll
    for (int cf = 0; cf < 8; ++cf) {
      *(uint2*)&htile[el][cf * 16 + kg * 4] =
          make_uint2(cvtpk(macc[cf][0], macc[cf][1]), cvtpk(macc[cf][2], macc[cf][3]));
    }
  }
  __syncthreads();   // barrier 2

  // ---- C: run-table segmented reduce on column pairs (b32 + pk adds) ----
  {
    const int nruns = runCnt;
    const int ntask = nruns << 6;            // nruns * 64 col-pairs
    for (int base = w * 64; base < ntask; base += 256) {
      const int run = base >> 6;             // wave-uniform
      const int cp = lane;                   // col pair 0..63
      const int s    = __builtin_amdgcn_readfirstlane(runStart[run]);
      const int epos = __builtin_amdgcn_readfirstlane(runStart[run + 1]);
      const int dd   = __builtin_amdgcn_readfirstlane(dsts[s]);
      f32x2 racc = {0.0f, 0.0f};
      for (int e = s; e < epos; ++e) {
        const unsigned vv = *(const unsigned*)&htile[e][cp * 2];
        f32x2 f; f[0] = uasf(vv << 16); f[1] = uasf(vv & 0xffff0000u);
        racc += f;
      }
      atomicAdd(sums + (size_t)dd * 128 + cp * 2,     racc[0]);
      atomicAdd(sums + (size_t)dd * 128 + cp * 2 + 1, racc[1]);
    }
  }
}

// ============ K3: GRU + LN2 (MFMA), 32 nodes per block, 8 waves ============
__global__ __launch_bounds__(512) void k3_gru(const float* __restrict__ x,
                                              const float* __restrict__ sums,
                                              const int* __restrict__ deg,
                                              const unsigned short* __restrict__ Wihf,
                                              const unsigned short* __restrict__ Whhf,
                                              const float* __restrict__ bih,
                                              const float* __restrict__ bhh,
                                              const float* __restrict__ b2,
                                              const float* __restrict__ ln2g,
                                              const float* __restrict__ ln2b,
                                              float* __restrict__ out) {
  __shared__ unsigned short aggb[32][136];
  __shared__ unsigned short Ss[32][776];
  const int t = threadIdx.x, lane = t & 63, w = t >> 6;
  const int kg = lane >> 4, li = lane & 15;
  const int n0 = blockIdx.x * 32;

  {
    const int nl = t >> 4, c0 = (t & 15) * 8;
    const int gn = n0 + nl;
    uint4 o = make_uint4(0, 0, 0, 0);
    if (gn < NN) {
      const int dc = deg[gn];
      const float inv = frcp(fmaxf((float)dc, 1.0f));
      const float bsc = (dc > 0) ? 1.0f : 0.0f;
      const float* sp = sums + (size_t)gn * 128 + c0;
      const float4 u = *(const float4*)sp, v = *(const float4*)(sp + 4);
      const float4 bu = *(const float4*)(b2 + c0), bv = *(const float4*)(b2 + c0 + 4);
      o.x = cvtpk(u.x * inv + bsc * bu.x, u.y * inv + bsc * bu.y);
      o.y = cvtpk(u.z * inv + bsc * bu.z, u.w * inv + bsc * bu.w);
      o.z = cvtpk(v.x * inv + bsc * bv.x, v.y * inv + bsc * bv.y);
      o.w = cvtpk(v.z * inv + bsc * bv.z, v.w * inv + bsc * bv.w);
    }
    *(uint4*)&aggb[nl][c0] = o;
  }
  __syncthreads();

  const int nh = w >> 2;
  const int isH = (w >> 1) & 1;
  const int ctbase = (w & 1) * 12;
  const int nodeL = nh * 16 + li;
  const int gnode = n0 + nodeL;
  const unsigned short* Wf = isH ? Whhf : Wihf;
  const float* bias = isH ? bhh : bih;
  const f32x4 zf = {0.0f, 0.0f, 0.0f, 0.0f};
  f32x4 acc[12];
#pragma unroll
  for (int i = 0; i < 12; ++i) acc[i] = zf;
#pragma unroll
  for (int ks = 0; ks < 4; ++ks) {
    bf16x8 bfrag;
    if (isH) {
      if (gnode < NN) {
        const float* xp = x + (size_t)gnode * 128 + ks * 32 + kg * 8;
        const float4 u = *(const float4*)xp, v = *(const float4*)(xp + 4);
        bfrag = pack8(u.x, u.y, u.z, u.w, v.x, v.y, v.z, v.w);
      } else {
        bfrag = pack8(0.f, 0.f, 0.f, 0.f, 0.f, 0.f, 0.f, 0.f);
      }
    } else {
      bfrag = *(const bf16x8*)&aggb[nodeL][ks * 32 + kg * 8];
    }
#pragma unroll
    for (int i = 0; i < 12; ++i) {
      const int ct = ctbase + i;
      const bf16x8 af = *(const bf16x8*)(Wf + (size_t)(ct * 4 + ks) * 512 + lane * 8);
      acc[i] = __builtin_amdgcn_mfma_f32_16x16x32_bf16(af, bfrag, acc[i], 0, 0, 0);
    }
  }
#pragma unroll
  for (int i = 0; i < 12; ++i) {
    const int ocol = (ctbase + i) * 16 + kg * 4;
    const float4 bb = *(const float4*)(bias + ocol);
    const int col = isH * 384 + ocol;
    const unsigned lo = cvtpk(acc[i][0] + bb.x, acc[i][1] + bb.y);
    const unsigned hi = cvtpk(acc[i][2] + bb.z, acc[i][3] + bb.w);
    *(uint2*)&Ss[nodeL][col] = make_uint2(lo, hi);
  }
  __syncthreads();

  const int nl = t >> 4, q0 = (t & 15) * 8;
  const int gn = n0 + nl;
  if (gn < NN) {
    float xv[8];
    *(float4*)&xv[0] = *(const float4*)(x + (size_t)gn * 128 + q0);
    *(float4*)&xv[4] = *(const float4*)(x + (size_t)gn * 128 + q0 + 4);
    const uint4 gir = *(const uint4*)&Ss[nl][q0];
    const uint4 giz = *(const uint4*)&Ss[nl][q0 + 128];
    const uint4 gin = *(const uint4*)&Ss[nl][q0 + 256];
    const uint4 ghr = *(const uint4*)&Ss[nl][q0 + 384];
    const uint4 ghz = *(const uint4*)&Ss[nl][q0 + 512];
    const uint4 ghn = *(const uint4*)&Ss[nl][q0 + 640];
    const unsigned GIR[4] = {gir.x, gir.y, gir.z, gir.w};
    const unsigned GIZ[4] = {giz.x, giz.y, giz.z, giz.w};
    const unsigned GIN[4] = {gin.x, gin.y, gin.z, gin.w};
    const unsigned GHR[4] = {ghr.x, ghr.y, ghr.z, ghr.w};
    const unsigned GHZ[4] = {ghz.x, ghz.y, ghz.z, ghz.w};
    const unsigned GHN[4] = {ghn.x, ghn.y, ghn.z, ghn.w};
    float vb[8];
    float s1 = 0.0f, s2 = 0.0f;
#pragma unroll
    for (int j2 = 0; j2 < 4; ++j2) {
#pragma unroll
      for (int hl = 0; hl < 2; ++hl) {
        const int jj = j2 * 2 + hl;
        const unsigned sh = hl * 16;
        const float girv = bf2f((GIR[j2] >> sh) & 0xffffu);
        const float gizv = bf2f((GIZ[j2] >> sh) & 0xffffu);
        const float ginv = bf2f((GIN[j2] >> sh) & 0xffffu);
        const float ghrv = bf2f((GHR[j2] >> sh) & 0xffffu);
        const float ghzv = bf2f((GHZ[j2] >> sh) & 0xffffu);
        const float ghnv = bf2f((GHN[j2] >> sh) & 0xffffu);
        const float r = sigm(girv + ghrv);
        const float z = sigm(gizv + ghzv);
        const float nv = ftanh(ginv + r * ghnv);
        const float v = xv[jj] + (1.0f - z) * nv + z * xv[jj];
        vb[jj] = v; s1 += v; s2 += v * v;
      }
    }
    s1 += __shfl_xor(s1, 1); s2 += __shfl_xor(s2, 1);
    s1 += __shfl_xor(s1, 2); s2 += __shfl_xor(s2, 2);
    s1 += __shfl_xor(s1, 4); s2 += __shfl_xor(s2, 4);
    s1 += __shfl_xor(s1, 8); s2 += __shfl_xor(s2, 8);
    const float m = s1 * (1.0f / 128.0f);
    const float var = s2 * (1.0f / 128.0f) - m * m;
    const float rstd = rsqrtf(var + 1e-5f);
    float ov[8];
#pragma unroll
    for (int j = 0; j < 8; ++j)
      ov[j] = ln2g[q0 + j] * ((vb[j] - m) * rstd) + ln2b[q0 + j];
    *(float4*)(out + (size_t)gn * 128 + q0) = make_float4(ov[0], ov[1], ov[2], ov[3]);
    *(float4*)(out + (size_t)gn * 128 + q0 + 4) = make_float4(ov[4], ov[5], ov[6], ov[7]);
  }
}

extern "C" void kernel_launch(void* const* d_in, const int* in_sizes, int n_in,
                              void* d_out, int out_size, void* d_ws, size_t ws_size,
                              hipStream_t stream) {
  const float* x         = (const float*)d_in[0];
  const float* edge_attr = (const float*)d_in[1];
  const float* pos       = (const float*)d_in[2];
  const float* W1        = (const float*)d_in[3];
  const float* b1        = (const float*)d_in[4];
  const float* ln1g      = (const float*)d_in[5];
  const float* ln1b      = (const float*)d_in[6];
  const float* W2        = (const float*)d_in[7];
  const float* b2        = (const float*)d_in[8];
  const float* Wih       = (const float*)d_in[9];
  const float* bih       = (const float*)d_in[10];
  const float* Whh       = (const float*)d_in[11];
  const float* bhh       = (const float*)d_in[12];
  const float* ln2g      = (const float*)d_in[13];
  const float* ln2b      = (const float*)d_in[14];
  const int*   ei        = (const int*)d_in[15];
  float* out = (float*)d_out;

  // ws layout (bytes); ws_size >= 109.9 MB proven (r10 f32p branch executed).
  float*          sums  = (float*)d_ws;                                   // 25,600,000
  int*            deg   = (int*)((char*)d_ws + 25600000);                 //    200,000
  int*            cur   = (int*)((char*)d_ws + 25800000);                 //    200,000
  unsigned short* Pdb   = (unsigned short*)((char*)d_ws + 26000000);      // 12,800,000
  unsigned short* Psb   = (unsigned short*)((char*)d_ws + 38800000);      // 12,800,000
  unsigned short* frags = (unsigned short*)((char*)d_ws + 51600000);      //    303,104
  int*            offs  = (int*)((char*)d_ws + 52000000);                 //    200,000
  int*            bsum  = (int*)((char*)d_ws + 52200000);                 //        784
  unsigned short* ea_s  = (unsigned short*)((char*)d_ws + 52300032);      // 38,400,000 -> 90.7MB
  unsigned short* W1ef = frags;               // 8 frags
  unsigned short* W2f  = frags + 8 * 512;     // 32 frags
  unsigned short* W1nf = frags + 40 * 512;    // 64 frags
  unsigned short* Wihf = frags + 104 * 512;   // 96 frags
  unsigned short* Whhf = frags + 200 * 512;   // 96 frags

  hipMemsetAsync(deg, 0, 400000, stream);       // deg + cur

  kM_hist_prep<<<3421, 256, 0, stream>>>(ei, deg, W1, W2, Wih, Whh, frags);
  kM_k1_partial<<<3321, 256, 0, stream>>>(x, W1nf, Pdb, Psb, deg, bsum, sums);
  kC_offs2<<<196, 256, 0, stream>>>(deg, bsum, offs);
  k_prep_edges<<<3125, 256, 0, stream>>>(ei, edge_attr, pos, offs, cur, ea_s);
  k2_edge<<<12500, 256, 0, stream>>>(Pdb, Psb, ea_s,
                                     W1ef, W2f, b1, ln1g, ln1b, sums);
  k3_gru<<<1563, 512, 0, stream>>>(x, sums, deg, Wihf, Whhf, bih, bhh, b2,
                                   ln2g, ln2b, out);
}